// Round 4
// baseline (87.957 us; speedup 1.0000x reference)
//
#include <hip/hip_runtime.h>
#include <hip/hip_bf16.h>

// B=8, N=256, D=128, H=256, K=128
// out[b,i,j,k] = exp(-(v - means[k])^2 * |temps[k]|)
//   v    = mul * x[b,i,j] + bias
//   mul  = (sum_h relu(hi[b,i,h]+hj[b,j,h]+b1[h]) * W2[h,0] + b2[0]) * 0.0625
//   bias = (                 "                    * W2[h,1] + b2[1]) * 0.0625

#define NB 8
#define NN 256
#define ND 128
#define NH 256
#define NK 128
#define GI 4   // i-rows per block in edge_rbf

typedef float f32x4 __attribute__((ext_vector_type(4)));

// ---------------- Kernel A: hi[bi][h] and hjbT[b][h][j] = hj + b1 ----------------
__global__ __launch_bounds__(256) void precompute_hij(
    const float* __restrict__ atom, const float* __restrict__ W1,
    const float* __restrict__ b1,
    float* __restrict__ hi, float* __restrict__ hjbT) {
  const int h = threadIdx.x;          // 0..255
  const int base = blockIdx.x * 8;    // bn base (multiple of 8 -> same b)
  const int b  = base >> 8;
  const int j0 = base & 255;
  __shared__ float a[8][ND];
  for (int t = threadIdx.x; t < 8 * ND; t += 256) {
    a[t >> 7][t & 127] = atom[(size_t)base * ND + t];
  }
  __syncthreads();
  float acc0[8], acc1[8];
  const float bv = b1[h];
#pragma unroll
  for (int r = 0; r < 8; ++r) { acc0[r] = 0.f; acc1[r] = bv; }
  for (int d = 0; d < ND; ++d) {
    const float w0 = W1[d * NH + h];
    const float w1 = W1[(ND + d) * NH + h];
#pragma unroll
    for (int r = 0; r < 8; ++r) {
      acc0[r] = fmaf(a[r][d], w0, acc0[r]);
      acc1[r] = fmaf(a[r][d], w1, acc1[r]);
    }
  }
#pragma unroll
  for (int r = 0; r < 8; ++r) {
    hi[(size_t)(base + r) * NH + h] = acc0[r];
    hjbT[((size_t)b * NH + h) * NN + (j0 + r)] = acc1[r];
  }
}

// ---------------- Kernel B: GI i-rows per block ----------------
// grid = B*N/GI blocks; b = blockIdx&7 (XCD-L2 locality), 256 threads = 4 waves.
// Phase 1: wave w reduces h in [64w,64w+64) for all GI rows; lanes over j.
// Phase 2: per row, wave w covers j in [64w,+64); lane: k0=4(l&31), jhalf=l>>5.
__global__ __launch_bounds__(256) void edge_rbf(
    const float* __restrict__ x,
    const float* __restrict__ hi, const float* __restrict__ hjbT,
    const float* __restrict__ W2, const float* __restrict__ b2,
    const float* __restrict__ means, const float* __restrict__ temps,
    float* __restrict__ out) {
  const int b    = blockIdx.x & 7;
  const int i0   = (blockIdx.x >> 3) * GI;
  const int lane = threadIdx.x & 63;
  const int wave = threadIdx.x >> 6;

  __shared__ float part0[4][GI][NN];
  __shared__ float part1[4][GI][NN];
  __shared__ float vsh[GI][NN];

  // ---- Phase 1 ----
  const float* __restrict__ hjrow  = hjbT + ((size_t)b * NH + wave * 64) * NN;
  const float* __restrict__ w2row  = W2 + wave * 128;
  const float* __restrict__ hibase = hi + ((size_t)(b * NN + i0)) * NH + wave * 64;

  float acc0[GI][4], acc1[GI][4];
#pragma unroll
  for (int r = 0; r < GI; ++r)
#pragma unroll
    for (int q = 0; q < 4; ++q) { acc0[r][q] = 0.f; acc1[r][q] = 0.f; }

#pragma unroll 4
  for (int hh = 0; hh < 64; ++hh) {
    const float4 hj4 = *reinterpret_cast<const float4*>(hjrow + (size_t)hh * NN + 4 * lane);
    const float w0 = w2row[2 * hh];
    const float w1 = w2row[2 * hh + 1];
#pragma unroll
    for (int r = 0; r < GI; ++r) {
      const float hih = hibase[(size_t)r * NH + hh];  // wave-uniform
      const float a0 = fmaxf(hih + hj4.x, 0.f);
      const float a1 = fmaxf(hih + hj4.y, 0.f);
      const float a2 = fmaxf(hih + hj4.z, 0.f);
      const float a3 = fmaxf(hih + hj4.w, 0.f);
      acc0[r][0] = fmaf(a0, w0, acc0[r][0]); acc1[r][0] = fmaf(a0, w1, acc1[r][0]);
      acc0[r][1] = fmaf(a1, w0, acc0[r][1]); acc1[r][1] = fmaf(a1, w1, acc1[r][1]);
      acc0[r][2] = fmaf(a2, w0, acc0[r][2]); acc1[r][2] = fmaf(a2, w1, acc1[r][2]);
      acc0[r][3] = fmaf(a3, w0, acc0[r][3]); acc1[r][3] = fmaf(a3, w1, acc1[r][3]);
    }
  }
#pragma unroll
  for (int r = 0; r < GI; ++r) {
    *reinterpret_cast<float4*>(&part0[wave][r][4 * lane]) =
        make_float4(acc0[r][0], acc0[r][1], acc0[r][2], acc0[r][3]);
    *reinterpret_cast<float4*>(&part1[wave][r][4 * lane]) =
        make_float4(acc1[r][0], acc1[r][1], acc1[r][2], acc1[r][3]);
  }
  __syncthreads();

  // ---- Cross-wave reduce + v = mul*x + bias ----
  {
    const int t = threadIdx.x;
    const float scale = 0.0625f;
    const float b20 = b2[0], b21 = b2[1];
#pragma unroll
    for (int r = 0; r < GI; ++r) {
      const float s0 = part0[0][r][t] + part0[1][r][t] + part0[2][r][t] + part0[3][r][t];
      const float s1 = part1[0][r][t] + part1[1][r][t] + part1[2][r][t] + part1[3][r][t];
      const float mul  = (s0 + b20) * scale;
      const float bias = (s1 + b21) * scale;
      vsh[r][t] = fmaf(mul, x[(size_t)(b * NN + i0 + r) * NN + t], bias);
    }
  }
  __syncthreads();

  // ---- Phase 2: RBF + nontemporal store ----
  const int k0 = (lane & 31) * 4;
  const int jhalf = lane >> 5;
  const float LOG2E = 1.44269504088896340736f;
  const float4 mv = *reinterpret_cast<const float4*>(means + k0);
  float4 tv = *reinterpret_cast<const float4*>(temps + k0);
  tv.x = -fabsf(tv.x) * LOG2E;
  tv.y = -fabsf(tv.y) * LOG2E;
  tv.z = -fabsf(tv.z) * LOG2E;
  tv.w = -fabsf(tv.w) * LOG2E;

#pragma unroll
  for (int r = 0; r < GI; ++r) {
    float* __restrict__ orow = out + ((size_t)(b * NN + i0 + r) * NN + wave * 64) * NK;
#pragma unroll 4
    for (int c = 0; c < 32; ++c) {
      const int j = 2 * c + jhalf;
      const float vj = vsh[r][wave * 64 + j];
      const float d0 = vj - mv.x;
      const float d1 = vj - mv.y;
      const float d2 = vj - mv.z;
      const float d3 = vj - mv.w;
      f32x4 e;
      e.x = __builtin_amdgcn_exp2f(d0 * d0 * tv.x);
      e.y = __builtin_amdgcn_exp2f(d1 * d1 * tv.y);
      e.z = __builtin_amdgcn_exp2f(d2 * d2 * tv.z);
      e.w = __builtin_amdgcn_exp2f(d3 * d3 * tv.w);
      __builtin_nontemporal_store(e, reinterpret_cast<f32x4*>(orow + (size_t)j * NK + k0));
    }
  }
}

extern "C" void kernel_launch(void* const* d_in, const int* in_sizes, int n_in,
                              void* d_out, int out_size, void* d_ws, size_t ws_size,
                              hipStream_t stream) {
  const float* x     = (const float*)d_in[0];
  const float* atom  = (const float*)d_in[1];
  const float* W1    = (const float*)d_in[2];
  const float* b1    = (const float*)d_in[3];
  const float* W2    = (const float*)d_in[4];
  const float* b2    = (const float*)d_in[5];
  const float* means = (const float*)d_in[6];
  const float* temps = (const float*)d_in[7];
  float* out = (float*)d_out;

  float* hi   = (float*)d_ws;                        // 2 MB: [B*N][H]
  float* hjbT = hi + (size_t)NB * NN * NH;           // 2 MB: [B][H][N]

  precompute_hij<<<NB * NN / 8, 256, 0, stream>>>(atom, W1, b1, hi, hjbT);
  edge_rbf<<<NB * NN / GI, 256, 0, stream>>>(x, hi, hjbT, W2, b2, means, temps, out);
}

// Round 5
// 73.331 us; speedup vs baseline: 1.1995x; 1.1995x over previous
//
#include <hip/hip_runtime.h>
#include <hip/hip_bf16.h>

// B=8, N=256, D=128, H=256, K=128
// out[b,i,j,k] = exp(-(v - means[k])^2 * |temps[k]|)
//   v    = mul * x[b,i,j] + bias
//   mul  = (sum_h relu(hi[b,i,h]+hj[b,j,h]+b1[h]) * W2[h,0] + b2[0]) * 0.0625
//   bias = (                 "                    * W2[h,1] + b2[1]) * 0.0625

#define NB 8
#define NN 256
#define ND 128
#define NH 256
#define NK 128
#define GI 2   // i-rows per block in edge_rbf (GI=4 collapsed occupancy in R4)

// ---------------- Kernel A: hi[bi][h] and hjbT[b][h][j] = hj + b1 ----------------
__global__ __launch_bounds__(256) void precompute_hij(
    const float* __restrict__ atom, const float* __restrict__ W1,
    const float* __restrict__ b1,
    float* __restrict__ hi, float* __restrict__ hjbT) {
  const int h = threadIdx.x;          // 0..255
  const int base = blockIdx.x * 8;    // bn base (multiple of 8 -> same b)
  const int b  = base >> 8;
  const int j0 = base & 255;
  __shared__ float a[8][ND];
  for (int t = threadIdx.x; t < 8 * ND; t += 256) {
    a[t >> 7][t & 127] = atom[(size_t)base * ND + t];
  }
  __syncthreads();
  float acc0[8], acc1[8];
  const float bv = b1[h];
#pragma unroll
  for (int r = 0; r < 8; ++r) { acc0[r] = 0.f; acc1[r] = bv; }
  for (int d = 0; d < ND; ++d) {
    const float w0 = W1[d * NH + h];
    const float w1 = W1[(ND + d) * NH + h];
#pragma unroll
    for (int r = 0; r < 8; ++r) {
      acc0[r] = fmaf(a[r][d], w0, acc0[r]);
      acc1[r] = fmaf(a[r][d], w1, acc1[r]);
    }
  }
#pragma unroll
  for (int r = 0; r < 8; ++r) {
    hi[(size_t)(base + r) * NH + h] = acc0[r];
    hjbT[((size_t)b * NH + h) * NN + (j0 + r)] = acc1[r];
  }
}

// ---------------- Kernel B: GI i-rows per block ----------------
// grid = B*N/GI blocks; b = blockIdx&7 (XCD-L2 locality), 256 threads = 4 waves.
// Phase 1: wave w reduces h in [64w,64w+64) for all GI rows; lanes over j.
// Phase 2: per row, wave w covers j in [64w,+64); lane: k0=4(l&31), jhalf=l>>5.
__global__ __launch_bounds__(256) void edge_rbf(
    const float* __restrict__ x,
    const float* __restrict__ hi, const float* __restrict__ hjbT,
    const float* __restrict__ W2, const float* __restrict__ b2,
    const float* __restrict__ means, const float* __restrict__ temps,
    float* __restrict__ out) {
  const int b    = blockIdx.x & 7;
  const int i0   = (blockIdx.x >> 3) * GI;
  const int lane = threadIdx.x & 63;
  const int wave = threadIdx.x >> 6;

  __shared__ float part0[4][GI][NN];   // 8 KB
  __shared__ float part1[4][GI][NN];   // 8 KB
  __shared__ float vsh[GI][NN];        // 2 KB

  // ---- Phase 1 ----
  const float* __restrict__ hjrow  = hjbT + ((size_t)b * NH + wave * 64) * NN;
  const float* __restrict__ w2row  = W2 + wave * 128;
  const float* __restrict__ hibase = hi + ((size_t)(b * NN + i0)) * NH + wave * 64;

  float acc0[GI][4], acc1[GI][4];
#pragma unroll
  for (int r = 0; r < GI; ++r)
#pragma unroll
    for (int q = 0; q < 4; ++q) { acc0[r][q] = 0.f; acc1[r][q] = 0.f; }

#pragma unroll 8
  for (int hh = 0; hh < 64; ++hh) {
    const float4 hj4 = *reinterpret_cast<const float4*>(hjrow + (size_t)hh * NN + 4 * lane);
    const float w0 = w2row[2 * hh];
    const float w1 = w2row[2 * hh + 1];
#pragma unroll
    for (int r = 0; r < GI; ++r) {
      const float hih = hibase[(size_t)r * NH + hh];  // wave-uniform
      const float a0 = fmaxf(hih + hj4.x, 0.f);
      const float a1 = fmaxf(hih + hj4.y, 0.f);
      const float a2 = fmaxf(hih + hj4.z, 0.f);
      const float a3 = fmaxf(hih + hj4.w, 0.f);
      acc0[r][0] = fmaf(a0, w0, acc0[r][0]); acc1[r][0] = fmaf(a0, w1, acc1[r][0]);
      acc0[r][1] = fmaf(a1, w0, acc0[r][1]); acc1[r][1] = fmaf(a1, w1, acc1[r][1]);
      acc0[r][2] = fmaf(a2, w0, acc0[r][2]); acc1[r][2] = fmaf(a2, w1, acc1[r][2]);
      acc0[r][3] = fmaf(a3, w0, acc0[r][3]); acc1[r][3] = fmaf(a3, w1, acc1[r][3]);
    }
  }
#pragma unroll
  for (int r = 0; r < GI; ++r) {
    *reinterpret_cast<float4*>(&part0[wave][r][4 * lane]) =
        make_float4(acc0[r][0], acc0[r][1], acc0[r][2], acc0[r][3]);
    *reinterpret_cast<float4*>(&part1[wave][r][4 * lane]) =
        make_float4(acc1[r][0], acc1[r][1], acc1[r][2], acc1[r][3]);
  }
  __syncthreads();

  // ---- Cross-wave reduce + v = mul*x + bias ----
  {
    const int t = threadIdx.x;
    const float scale = 0.0625f;
    const float b20 = b2[0], b21 = b2[1];
#pragma unroll
    for (int r = 0; r < GI; ++r) {
      const float s0 = part0[0][r][t] + part0[1][r][t] + part0[2][r][t] + part0[3][r][t];
      const float s1 = part1[0][r][t] + part1[1][r][t] + part1[2][r][t] + part1[3][r][t];
      const float mul  = (s0 + b20) * scale;
      const float bias = (s1 + b21) * scale;
      vsh[r][t] = fmaf(mul, x[(size_t)(b * NN + i0 + r) * NN + t], bias);
    }
  }
  __syncthreads();

  // ---- Phase 2: RBF + store (plain stores through L2 — NT regressed in R4) ----
  const int k0 = (lane & 31) * 4;
  const int jhalf = lane >> 5;
  const float LOG2E = 1.44269504088896340736f;
  const float4 mv = *reinterpret_cast<const float4*>(means + k0);
  float4 tv = *reinterpret_cast<const float4*>(temps + k0);
  tv.x = -fabsf(tv.x) * LOG2E;
  tv.y = -fabsf(tv.y) * LOG2E;
  tv.z = -fabsf(tv.z) * LOG2E;
  tv.w = -fabsf(tv.w) * LOG2E;

#pragma unroll
  for (int r = 0; r < GI; ++r) {
    float* __restrict__ orow = out + ((size_t)(b * NN + i0 + r) * NN + wave * 64) * NK;
#pragma unroll 4
    for (int c = 0; c < 32; ++c) {
      const int j = 2 * c + jhalf;
      const float vj = vsh[r][wave * 64 + j];
      const float d0 = vj - mv.x;
      const float d1 = vj - mv.y;
      const float d2 = vj - mv.z;
      const float d3 = vj - mv.w;
      float4 e;
      e.x = __builtin_amdgcn_exp2f(d0 * d0 * tv.x);
      e.y = __builtin_amdgcn_exp2f(d1 * d1 * tv.y);
      e.z = __builtin_amdgcn_exp2f(d2 * d2 * tv.z);
      e.w = __builtin_amdgcn_exp2f(d3 * d3 * tv.w);
      *reinterpret_cast<float4*>(orow + (size_t)j * NK + k0) = e;
    }
  }
}

extern "C" void kernel_launch(void* const* d_in, const int* in_sizes, int n_in,
                              void* d_out, int out_size, void* d_ws, size_t ws_size,
                              hipStream_t stream) {
  const float* x     = (const float*)d_in[0];
  const float* atom  = (const float*)d_in[1];
  const float* W1    = (const float*)d_in[2];
  const float* b1    = (const float*)d_in[3];
  const float* W2    = (const float*)d_in[4];
  const float* b2    = (const float*)d_in[5];
  const float* means = (const float*)d_in[6];
  const float* temps = (const float*)d_in[7];
  float* out = (float*)d_out;

  float* hi   = (float*)d_ws;                        // 2 MB: [B*N][H]
  float* hjbT = hi + (size_t)NB * NN * NH;           // 2 MB: [B][H][N]

  precompute_hij<<<NB * NN / 8, 256, 0, stream>>>(atom, W1, b1, hi, hjbT);
  edge_rbf<<<NB * NN / GI, 256, 0, stream>>>(x, hi, hjbT, W2, b2, means, temps, out);
}